// Round 11
// baseline (449.031 us; speedup 1.0000x reference)
//
#include <hip/hip_runtime.h>
#include <math.h>

// x: [8][64][256][256] f32 ; w1/w2: [2][32][32][32] f32 (re,im separate)
// Pipeline (all linear ops commute across tensor factors):
//   K1 w_fwd : DFT_W (folded) + mixW -> Yw[c][h][64]   (64 = 32 Re | 32 Im w-modes)
//   K2 h_fwd : DFT_H (folded)        -> Z [bg,kh,o][128] (64 Re_h | 64 Im_h slots)
//   K3 h_mix2: mixH                  -> Z2[c][kh][128]
//   K4 h_inv2: IDFT_H (mirror)       -> YH[c][h][64]   (reuses Yw region)
//   K5 w_inv2: IDFT_W (mirror)       -> out
// R11: 512-thread blocks (same LDS/block -> 2x waves/CU) for K1/K2/K4/K5.
#define PI2_256 0.0245436926061702596754894014318f  // 2*pi/256
#define TS 260                                       // padded tile stride

// ---------------------------------------------------------------------------
__global__ __launch_bounds__(256) void init_tab(float* __restrict__ tc, float* __restrict__ ts) {
    int idx = blockIdx.x * 256 + threadIdx.x;   // 0..8191
    int k = idx >> 8, n = idx & 255;            // k < 32
    int m = (k * n) & 255;
    float s, c;
    sincosf(PI2_256 * (float)m, &s, &c);
    tc[idx] = c;
    ts[idx] = s;
}

// ---------------------------------------------------------------------------
// K1: per block = (b,g,xrow), 512 threads. folded DFT_W -> mixW -> global
// phase A map: hs = t&1 (h-half), kg = (t>>1)&15 (2 k's), rg = t>>5 (2 rows)
// ---------------------------------------------------------------------------
__global__ __launch_bounds__(512) void w_fwd(const float* __restrict__ x,
                                             const float* __restrict__ w2r,
                                             const float* __restrict__ w2i,
                                             float* __restrict__ Yw) {
    __shared__ float tile[32 * TS];                // folded in place
    __shared__ float XrL[32 * 36], XiL[32 * 36];   // [i][k], pad 36

    const int bid  = blockIdx.x;
    const int xrow = bid & 255;
    const int g    = (bid >> 8) & 1;
    const int b    = bid >> 9;
    const int t    = threadIdx.x;

    const size_t chan0 = (size_t)(b * 64 + g * 32);
    const size_t base  = (chan0 * 256 + xrow) * 256;       // + i*65536 + w

    // ---- stage input tile (coalesced float4); i = i0 + 8r ----
    {
        const int wq = t & 63, i0 = t >> 6;   // i0: 0..7
        #pragma unroll
        for (int r = 0; r < 4; ++r) {
            const int i = i0 + r * 8;
            *(float4*)(tile + i * TS + wq * 4) =
                *(const float4*)(x + base + (size_t)i * 65536 + wq * 4);
        }
    }
    __syncthreads();

    // ---- fold prepass (in place, gather-free): rows i0, i0+16 ----
    {
        const int hq = t & 31, i0 = t >> 5;   // i0: 0..15
        const int h0 = hq * 4;
        float4 A[2], B[2]; float c0[2], x128v[2];
        #pragma unroll
        for (int r = 0; r < 2; ++r) {
            const float* row = tile + (i0 + r * 16) * TS;
            A[r] = *(const float4*)(row + h0);               // x[4hq..4hq+3]
            B[r] = *(const float4*)(row + 4 * (63 - hq));    // x[252-4hq..255-4hq]
            x128v[r] = row[128];
        }
        #pragma unroll
        for (int r = 0; r < 2; ++r) {
            // mirror m = {x[256-4hq], B.w, B.z, B.y}; x[256-4hq] = lane(hq-1).B.x
            const float up = __shfl_up(B[r].x, 1);
            c0[r] = (hq == 0) ? A[r].x : up;                 // hq==0: x[0]=A.x
        }
        __syncthreads();
        #pragma unroll
        for (int r = 0; r < 2; ++r) {
            float* row = tile + (i0 + r * 16) * TS;
            float4 ye = make_float4(A[r].x + c0[r], A[r].y + B[r].w,
                                    A[r].z + B[r].z, A[r].w + B[r].y);
            float4 yo = make_float4(A[r].x - c0[r], A[r].y - B[r].w,
                                    A[r].z - B[r].z, A[r].w - B[r].y);
            if (hq == 0) yo.x = x128v[r];                    // stash x128 (s0=0 slot)
            *(float4*)(row + h0)       = ye;
            *(float4*)(row + 128 + h0) = yo;
        }
    }
    __syncthreads();

    // ---- phase A: folded DFT, Chebyshev; 2 k x 2 rows x h-half per thread ----
    {
        const int hs = t & 1;                    // h-half: h in [hs*64, hs*64+64)
        const int kg = (t >> 1) & 15;            // k = kg + 16*kk
        const int rg = t >> 5;                   // rows 2rg, 2rg+1 (rg 0..15)
        const float* rp0 = tile + (2 * rg) * TS;
        const float* rp1 = rp0 + TS;
        const float sgn = (kg & 1) ? -1.f : 1.f; // (-1)^k, k parity = kg parity
        const int hb = hs * 64;

        float cA[2], sA[2], cB[2], sB[2], t2[2];
        float xr[2][2], xi[2][2];
        #pragma unroll
        for (int kk = 0; kk < 2; ++kk) {
            const int k = kg + 16 * kk;
            float sd, cd; sincosf(PI2_256 * (float)k, &sd, &cd);
            t2[kk] = 2.f * cd;
            float ss, cc;
            sincosf(PI2_256 * (float)((k * hb) & 255), &ss, &cc);
            cA[kk] = cc; sA[kk] = ss;
            sincosf(PI2_256 * (float)((k * (hb - 1)) & 255), &ss, &cc);
            cB[kk] = cc; sB[kk] = ss;
        }
        const float x0_0 = rp0[0] * 0.5f, x128_0 = rp0[128];
        const float x0_1 = rp1[0] * 0.5f, x128_1 = rp1[128];
        #pragma unroll
        for (int kk = 0; kk < 2; ++kk) {
            xr[kk][0] = (hs == 0) ? (sgn * x128_0 - x0_0) : 0.f;
            xr[kk][1] = (hs == 0) ? (sgn * x128_1 - x0_1) : 0.f;
            xi[kk][0] = 0.f; xi[kk][1] = 0.f;
        }
        for (int hq = 0; hq < 16; ++hq) {
            const float4 ye0 = *(const float4*)(rp0 + hb + hq * 4);
            const float4 yo0 = *(const float4*)(rp0 + 128 + hb + hq * 4);
            const float4 ye1 = *(const float4*)(rp1 + hb + hq * 4);
            const float4 yo1 = *(const float4*)(rp1 + 128 + hb + hq * 4);
            #pragma unroll
            for (int j = 0; j < 4; ++j) {
                const float e0 = (&ye0.x)[j], o0 = (&yo0.x)[j];
                const float e1 = (&ye1.x)[j], o1 = (&yo1.x)[j];
                #pragma unroll
                for (int kk = 0; kk < 2; ++kk) {
                    xr[kk][0] += e0 * cA[kk];  xi[kk][0] -= o0 * sA[kk];
                    xr[kk][1] += e1 * cA[kk];  xi[kk][1] -= o1 * sA[kk];
                    const float cn = t2[kk] * cA[kk] - cB[kk]; cB[kk] = cA[kk]; cA[kk] = cn;
                    const float sn = t2[kk] * sA[kk] - sB[kk]; sB[kk] = sA[kk]; sA[kk] = sn;
                }
            }
        }
        // combine the two h-halves (lane pairs differ in bit 0)
        #pragma unroll
        for (int kk = 0; kk < 2; ++kk)
            #pragma unroll
            for (int r = 0; r < 2; ++r) {
                xr[kk][r] += __shfl_xor(xr[kk][r], 1);
                xi[kk][r] += __shfl_xor(xi[kk][r], 1);
            }
        if (hs == 0) {
            #pragma unroll
            for (int kk = 0; kk < 2; ++kk) {
                const int k = kg + 16 * kk;
                XrL[(2 * rg    ) * 36 + k] = xr[kk][0];
                XiL[(2 * rg    ) * 36 + k] = xi[kk][0];
                XrL[(2 * rg + 1) * 36 + k] = xr[kk][1];
                XiL[(2 * rg + 1) * 36 + k] = xi[kk][1];
            }
        }
    }
    __syncthreads();

    // ---- phase B: mixW, scale folded; k-pair per thread (16 kp x 32 o) ----
    {
        const int kp = t & 15;                   // k2 = 2*kp
        const int o  = t >> 4;                   // 0..31
        const int k2 = kp * 2;
        float2 ar = {0, 0}, ai = {0, 0};
        const float* wrb = w2r + (size_t)g * 32768 + o * 32 + k2;   // + i*1024
        const float* wib = w2i + (size_t)g * 32768 + o * 32 + k2;
        for (int i = 0; i < 32; ++i) {
            const float2 xr = *(const float2*)(XrL + i * 36 + k2);
            const float2 xi = *(const float2*)(XiL + i * 36 + k2);
            const float2 wr = *(const float2*)(wrb + i * 1024);
            const float2 wi = *(const float2*)(wib + i * 1024);
            ar.x += xr.x * wr.x - xi.x * wi.x;  ai.x += xr.x * wi.x + xi.x * wr.x;
            ar.y += xr.y * wr.y - xi.y * wi.y;  ai.y += xr.y * wi.y + xi.y * wr.y;
        }
        const float s2 = 2.f / 256.f, s1 = 1.f / 256.f;
        const float sx = (kp == 0) ? s1 : s2;    // element .x has k = 2kp
        float* dst = Yw + (size_t)((b * 2 + g) * 32 + o) * 16384 + (size_t)xrow * 64 + k2;
        *(float2*)(dst)      = make_float2(ar.x * sx, ar.y * s2);
        *(float2*)(dst + 32) = make_float2(ai.x * sx, ai.y * s2);
    }
}

// ---------------------------------------------------------------------------
// K2: folded DFT_H per channel c, 512 threads. Chebyshev (sincosf seeds).
// map: hs = t&1 (h-half), kg = (t>>1)&15 (2 k's), sp = t>>5 (slot quad 0..15)
// Z layout: [(bg*32 + kh)*32 + o][128]  (Re_h | Im_h)
// ---------------------------------------------------------------------------
__global__ __launch_bounds__(512) void h_fwd(const float* __restrict__ Yw,
                                             float* __restrict__ Z) {
    __shared__ float YL[256 * 64];   // 64 KB
    const int bid = blockIdx.x;      // (b*2+g)*32 + o
    const int t = threadIdx.x;
    {
        const float* src = Yw + (size_t)bid * 16384;
        #pragma unroll
        for (int r = 0; r < 8; ++r) {
            const int f = t + r * 512;
            *(float4*)(YL + f * 4) = *(const float4*)(src + f * 4);
        }
    }
    __syncthreads();

    const int hs = t & 1, kg = (t >> 1) & 15, sp = t >> 5;  // sp: 0..15
    const int hb = hs * 64;
    const float sgn = (kg & 1) ? -1.f : 1.f;                // (-1)^k
    const float4 y0q   = *(const float4*)(YL + sp * 4);
    const float4 y128q = *(const float4*)(YL + 128 * 64 + sp * 4);

    float cA[2], sA[2], cB[2], sB[2], t2[2];
    float xr[2][4], xi[2][4];
    #pragma unroll
    for (int kk = 0; kk < 2; ++kk) {
        const int k = kg + 16 * kk;
        float sd, cd; sincosf(PI2_256 * (float)k, &sd, &cd);
        t2[kk] = 2.f * cd;
        float ss, cc;
        sincosf(PI2_256 * (float)((k * hb) & 255), &ss, &cc);
        cA[kk] = cc; sA[kk] = ss;
        sincosf(PI2_256 * (float)((k * (hb - 1)) & 255), &ss, &cc);
        cB[kk] = cc; sB[kk] = ss;
        #pragma unroll
        for (int j = 0; j < 4; ++j) {
            xr[kk][j] = (hs == 0) ? (sgn * (&y128q.x)[j] - (&y0q.x)[j]) : 0.f;
            xi[kk][j] = 0.f;
        }
    }
    for (int h = hb; h < hb + 64; ++h) {
        const float4 aq = *(const float4*)(YL + h * 64 + sp * 4);
        const float4 mq = *(const float4*)(YL + ((256 - h) & 255) * 64 + sp * 4);
        float ye[4], yo[4];
        #pragma unroll
        for (int j = 0; j < 4; ++j) {
            ye[j] = (&aq.x)[j] + (&mq.x)[j];
            yo[j] = (&aq.x)[j] - (&mq.x)[j];
        }
        #pragma unroll
        for (int kk = 0; kk < 2; ++kk) {
            #pragma unroll
            for (int j = 0; j < 4; ++j) {
                xr[kk][j] += ye[j] * cA[kk];
                xi[kk][j] -= yo[j] * sA[kk];
            }
            const float cn = t2[kk] * cA[kk] - cB[kk]; cB[kk] = cA[kk]; cA[kk] = cn;
            const float sn = t2[kk] * sA[kk] - sB[kk]; sB[kk] = sA[kk]; sA[kk] = sn;
        }
    }
    // combine h-halves (lane pairs)
    #pragma unroll
    for (int kk = 0; kk < 2; ++kk)
        #pragma unroll
        for (int j = 0; j < 4; ++j) {
            xr[kk][j] += __shfl_xor(xr[kk][j], 1);
            xi[kk][j] += __shfl_xor(xi[kk][j], 1);
        }
    if (hs == 0) {
        const int o = bid & 31, bg = bid >> 5;
        #pragma unroll
        for (int kk = 0; kk < 2; ++kk) {
            const int k = kg + 16 * kk;
            const size_t zi_ = (((size_t)bg * 32 + k) * 32 + o) * 128 + sp * 4;
            *(float4*)(Z + zi_)      = make_float4(xr[kk][0], xr[kk][1], xr[kk][2], xr[kk][3]);
            *(float4*)(Z + zi_ + 64) = make_float4(xi[kk][0], xi[kk][1], xi[kk][2], xi[kk][3]);
        }
    }
}

// ---------------------------------------------------------------------------
// K3: mixH per (b,g,kh); H-ortho scale folded. Z2: [(bg*32+o)*32+kh][128]
// ---------------------------------------------------------------------------
__global__ __launch_bounds__(256) void h_mix2(const float* __restrict__ Z,
                                              const float* __restrict__ w1r,
                                              const float* __restrict__ w1i,
                                              float* __restrict__ Z2) {
    __shared__ float ZL[32 * 128];          // [i][128] 16 KB
    __shared__ float WrL[1024], WiL[1024];  // [i*32+o] 8 KB
    const int bid = blockIdx.x;             // bg*32 + kh
    const int kh = bid & 31, bg = bid >> 5;
    const int g = bg & 1;
    const int t = threadIdx.x;
    {
        const float* src = Z + (size_t)bid * 4096;
        #pragma unroll
        for (int r = 0; r < 4; ++r) {
            const int f = t + r * 256;
            *(float4*)(ZL + f * 4) = *(const float4*)(src + f * 4);
        }
        #pragma unroll
        for (int r = 0; r < 4; ++r) {
            const int idx = t + r * 256;    // i = idx>>5, o = idx&31
            const int gidx = g * 32768 + (idx >> 5) * 1024 + (idx & 31) * 32 + kh;
            WrL[idx] = w1r[gidx];
            WiL[idx] = w1i[gidx];
        }
    }
    __syncthreads();

    const int s = t & 63, og = t >> 6;      // o = og*8 + m
    float accr[8], acci[8];
    #pragma unroll
    for (int m = 0; m < 8; ++m) { accr[m] = 0.f; acci[m] = 0.f; }
    for (int i = 0; i < 32; ++i) {
        const float zr = ZL[i * 128 + s];
        const float zi = ZL[i * 128 + 64 + s];
        #pragma unroll
        for (int m = 0; m < 8; ++m) {
            const int o = og * 8 + m;
            const float wr = WrL[i * 32 + o];
            const float wi = WiL[i * 32 + o];
            accr[m] += zr * wr - zi * wi;
            acci[m] += zr * wi + zi * wr;
        }
    }
    const float sck = (kh == 0) ? (1.f / 256.f) : (2.f / 256.f);
    #pragma unroll
    for (int m = 0; m < 8; ++m) {
        const int o = og * 8 + m;
        const size_t zo = ((size_t)(bg * 32 + o) * 32 + kh) * 128 + s;
        Z2[zo]      = accr[m] * sck;
        Z2[zo + 64] = acci[m] * sck;
    }
}

// ---------------------------------------------------------------------------
// K4: IDFT_H (mirror, Nyquist) per channel c, 512 threads. Trig in LDS.
// Z2[c][kh][128] -> YHg[c][h][64]   (YHg reuses the Yw region)
// ---------------------------------------------------------------------------
__global__ __launch_bounds__(512) void h_inv2(const float* __restrict__ Z2,
                                              const float* __restrict__ tc,
                                              const float* __restrict__ ts,
                                              float* __restrict__ YHg) {
    __shared__ float ZL[32 * 128];                  // 16 KB
    __shared__ float TcL[32 * 128], TsL[32 * 128];  // 16+16 KB (lower-half trig)
    const int bid = blockIdx.x;                     // channel c
    const int t = threadIdx.x;
    {
        const float* src = Z2 + (size_t)bid * 4096;
        #pragma unroll
        for (int r = 0; r < 2; ++r) {
            const int f = t + r * 512;
            *(float4*)(ZL + f * 4) = *(const float4*)(src + f * 4);
        }
        #pragma unroll
        for (int r = 0; r < 2; ++r) {
            const int q = t + r * 512;              // 0..1023
            const int k = q >> 5, hq = q & 31;
            *(float4*)(TcL + k * 128 + hq * 4) = *(const float4*)(tc + (size_t)k * 256 + hq * 4);
            *(float4*)(TsL + k * 128 + hq * 4) = *(const float4*)(ts + (size_t)k * 256 + hq * 4);
        }
    }
    __syncthreads();

    const int s = t & 63, hg = t >> 6;              // hg 0..7
    float zr[32], zi[32];
    #pragma unroll
    for (int k = 0; k < 32; ++k) {
        zr[k] = ZL[k * 128 + s];
        zi[k] = ZL[k * 128 + 64 + s];
    }
    float* dst = YHg + (size_t)bid * 16384;
    #pragma unroll
    for (int jq = 0; jq < 4; ++jq) {
        const int h0 = hg * 16 + jq * 4;            // 0..124
        float sC[4] = {0, 0, 0, 0}, sS[4] = {0, 0, 0, 0};
        #pragma unroll
        for (int k = 0; k < 32; ++k) {
            const float4 c4 = *(const float4*)(TcL + k * 128 + h0);  // wave-uniform
            const float4 s4 = *(const float4*)(TsL + k * 128 + h0);
            sC[0] += zr[k] * c4.x;  sS[0] += zi[k] * s4.x;
            sC[1] += zr[k] * c4.y;  sS[1] += zi[k] * s4.y;
            sC[2] += zr[k] * c4.z;  sS[2] += zi[k] * s4.z;
            sC[3] += zr[k] * c4.w;  sS[3] += zi[k] * s4.w;
        }
        #pragma unroll
        for (int jj = 0; jj < 4; ++jj) {
            const int h = h0 + jj;
            dst[h * 64 + s] = sC[jj] - sS[jj];
            if (h > 0) dst[(256 - h) * 64 + s] = sC[jj] + sS[jj];
        }
    }
    if (hg == 0) {                                  // Nyquist row h = 128
        float ny = 0.f;
        #pragma unroll
        for (int k = 0; k < 32; ++k) ny += (k & 1) ? -zr[k] : zr[k];
        dst[128 * 64 + s] = ny;
    }
}

// ---------------------------------------------------------------------------
// K5: IDFT_W (mirror, Nyquist), 512 threads. block = (c, hb): 32 h-rows.
// YHg[c][h][64] -> out[c][h][256]
// ---------------------------------------------------------------------------
__global__ __launch_bounds__(512) void w_inv2(const float* __restrict__ YHg,
                                              const float* __restrict__ tc,
                                              const float* __restrict__ ts,
                                              float* __restrict__ out) {
    __shared__ float YL[32 * 64];                   // 8 KB  [hl][64]
    __shared__ float TcL[32 * 128], TsL[32 * 128];  // 32 KB (lower-half trig)
    const int bid = blockIdx.x;
    const int hb = bid & 7, c = bid >> 3;
    const int t = threadIdx.x;
    {
        const float* src = YHg + (size_t)c * 16384 + hb * 2048;
        // 512 float4 total -> one per thread
        *(float4*)(YL + t * 4) = *(const float4*)(src + t * 4);
        #pragma unroll
        for (int r = 0; r < 2; ++r) {
            const int q = t + r * 512;              // 0..1023
            const int k = q >> 5, wq_ = q & 31;
            *(float4*)(TcL + k * 128 + wq_ * 4) = *(const float4*)(tc + (size_t)k * 256 + wq_ * 4);
            *(float4*)(TsL + k * 128 + wq_ * 4) = *(const float4*)(ts + (size_t)k * 256 + wq_ * 4);
        }
    }
    __syncthreads();

    const int wq = t & 31, hh = t >> 5;             // hh 0..15, 2 h-rows per thread
    const int w0 = wq * 4;
    float* outp = out + (size_t)c * 65536;

    float sC[2][4], sS[2][4];                       // [j][w-lane]
    #pragma unroll
    for (int j = 0; j < 2; ++j)
        #pragma unroll
        for (int jj = 0; jj < 4; ++jj) { sC[j][jj] = 0.f; sS[j][jj] = 0.f; }

    for (int k = 0; k < 32; ++k) {
        const float4 c4 = *(const float4*)(TcL + k * 128 + w0);
        const float4 s4 = *(const float4*)(TsL + k * 128 + w0);
        #pragma unroll
        for (int j = 0; j < 2; ++j) {
            const int hl = hh * 2 + j;
            const float R = YL[hl * 64 + k];
            const float I = YL[hl * 64 + 32 + k];
            sC[j][0] += R * c4.x;  sS[j][0] += I * s4.x;
            sC[j][1] += R * c4.y;  sS[j][1] += I * s4.y;
            sC[j][2] += R * c4.z;  sS[j][2] += I * s4.z;
            sC[j][3] += R * c4.w;  sS[j][3] += I * s4.w;
        }
    }
    #pragma unroll
    for (int j = 0; j < 2; ++j) {
        const int h = hb * 32 + hh * 2 + j;
        *(float4*)(outp + (size_t)h * 256 + w0) =
            make_float4(sC[j][0] - sS[j][0], sC[j][1] - sS[j][1],
                        sC[j][2] - sS[j][2], sC[j][3] - sS[j][3]);
        #pragma unroll
        for (int jj = 0; jj < 4; ++jj) {
            const int w = w0 + jj;
            if (w >= 1) outp[(size_t)h * 256 + 256 - w] = sC[j][jj] + sS[j][jj];
        }
    }
    if (wq == 0) {                                  // Nyquist column w = 128
        #pragma unroll
        for (int j = 0; j < 2; ++j) {
            const int hl = hh * 2 + j;
            const int h = hb * 32 + hl;
            float ny = 0.f;
            #pragma unroll
            for (int k = 0; k < 32; ++k) {
                const float R = YL[hl * 64 + k];
                ny += (k & 1) ? -R : R;
            }
            outp[(size_t)h * 256 + 128] = ny;
        }
    }
}

// ---------------------------------------------------------------------------
extern "C" void kernel_launch(void* const* d_in, const int* in_sizes, int n_in,
                              void* d_out, int out_size, void* d_ws, size_t ws_size,
                              hipStream_t stream) {
    const float* x   = (const float*)d_in[0];
    const float* w1r = (const float*)d_in[1];
    const float* w1i = (const float*)d_in[2];
    const float* w2r = (const float*)d_in[3];
    const float* w2i = (const float*)d_in[4];
    float* out = (float*)d_out;
    float* ws  = (float*)d_ws;

    float* tc = ws;                    //  8192 floats
    float* ts = ws + 8192;             //  8192 floats
    float* Yw = ws + 16384;            //  8,388,608 floats (33.5 MB) — reused as YHg
    float* Z  = Yw + 8388608;          //  2,097,152 floats ( 8.4 MB)
    float* Z2 = Z + 2097152;           //  2,097,152 floats ( 8.4 MB)

    init_tab<<<32, 256, 0, stream>>>(tc, ts);
    w_fwd<<<4096, 512, 0, stream>>>(x, w2r, w2i, Yw);
    h_fwd<<<512, 512, 0, stream>>>(Yw, Z);
    h_mix2<<<512, 256, 0, stream>>>(Z, w1r, w1i, Z2);
    h_inv2<<<512, 512, 0, stream>>>(Z2, tc, ts, Yw);   // Yw region reused as YH
    w_inv2<<<4096, 512, 0, stream>>>(Yw, tc, ts, out);
}

// Round 12
// 192.915 us; speedup vs baseline: 2.3276x; 2.3276x over previous
//
#include <hip/hip_runtime.h>
#include <math.h>

// x: [8][64][256][256] f32 ; w1/w2: [2][32][32][32] f32 (re,im separate)
// Pipeline (all linear ops commute across tensor factors):
//   K1 w_fwd : DFT_W (folded) + mixW -> Yw[c][h][64]   (64 = 32 Re | 32 Im w-modes)
//   K2 h_fwd : DFT_H (folded)        -> Z [bg,kh,o][128] (64 Re_h | 64 Im_h slots)
//   K3 h_mix2: mixH                  -> Z2[c][kh][128]
//   K4 h_inv2: IDFT_H (mirror)       -> YH[c][h][64]   (reuses Yw region)
//   K5 w_inv2: IDFT_W (mirror)       -> out  [R12: all-float4 stores via shfl]
#define PI2_256 0.0245436926061702596754894014318f  // 2*pi/256
#define TS 260                                       // padded tile stride

// ---------------------------------------------------------------------------
__global__ __launch_bounds__(256) void init_tab(float* __restrict__ tc, float* __restrict__ ts) {
    int idx = blockIdx.x * 256 + threadIdx.x;   // 0..8191
    int k = idx >> 8, n = idx & 255;            // k < 32
    int m = (k * n) & 255;
    float s, c;
    sincosf(PI2_256 * (float)m, &s, &c);
    tc[idx] = c;
    ts[idx] = s;
}

// ---------------------------------------------------------------------------
// K1: per block = (b,g,xrow). folded DFT_W -> mixW (scale folded) -> global
// phase A thread map: hs = t&1 (h-half), kg = (t>>1)&7 (4 k's), rg = t>>4 (2 rows)
// ---------------------------------------------------------------------------
__global__ __launch_bounds__(256) void w_fwd(const float* __restrict__ x,
                                             const float* __restrict__ w2r,
                                             const float* __restrict__ w2i,
                                             float* __restrict__ Yw) {
    __shared__ float tile[32 * TS];                // folded in place
    __shared__ float XrL[32 * 36], XiL[32 * 36];   // [i][k], pad 36

    const int bid  = blockIdx.x;
    const int xrow = bid & 255;
    const int g    = (bid >> 8) & 1;
    const int b    = bid >> 9;
    const int t    = threadIdx.x;

    const size_t chan0 = (size_t)(b * 64 + g * 32);
    const size_t base  = (chan0 * 256 + xrow) * 256;       // + i*65536 + w

    // ---- stage input tile (coalesced float4) ----
    {
        const int wq = t & 63, i0 = t >> 6;
        #pragma unroll
        for (int r = 0; r < 8; ++r) {
            const int i = i0 + r * 4;
            *(float4*)(tile + i * TS + wq * 4) =
                *(const float4*)(x + base + (size_t)i * 65536 + wq * 4);
        }
    }
    __syncthreads();

    // ---- fold prepass (in place, gather-free): mirror via aligned b128 + shfl.
    //      row[0..127]=ye (ye[0]=2x0), row[128]=x128, row[129..255]=yo ----
    {
        const int hq = t & 31, i0 = t >> 5;
        const int h0 = hq * 4;
        float4 A[4], B[4]; float c0[4], x128v[4];
        #pragma unroll
        for (int r = 0; r < 4; ++r) {
            const float* row = tile + (i0 + r * 8) * TS;
            A[r] = *(const float4*)(row + h0);               // x[4hq..4hq+3]
            B[r] = *(const float4*)(row + 4 * (63 - hq));    // x[252-4hq..255-4hq]
            x128v[r] = row[128];                             // broadcast (free)
        }
        #pragma unroll
        for (int r = 0; r < 4; ++r) {
            // mirror m = {x[256-4hq], B.w, B.z, B.y}; x[256-4hq] = lane(hq-1).B.x
            const float up = __shfl_up(B[r].x, 1);
            c0[r] = (hq == 0) ? A[r].x : up;                 // hq==0: x[0]=A.x
        }
        __syncthreads();
        #pragma unroll
        for (int r = 0; r < 4; ++r) {
            float* row = tile + (i0 + r * 8) * TS;
            float4 ye = make_float4(A[r].x + c0[r], A[r].y + B[r].w,
                                    A[r].z + B[r].z, A[r].w + B[r].y);
            float4 yo = make_float4(A[r].x - c0[r], A[r].y - B[r].w,
                                    A[r].z - B[r].z, A[r].w - B[r].y);
            if (hq == 0) yo.x = x128v[r];                    // stash x128 (s0=0 slot)
            *(float4*)(row + h0)       = ye;
            *(float4*)(row + 128 + h0) = yo;
        }
    }
    __syncthreads();

    // ---- phase A: folded DFT, Chebyshev; 4 k x 2 rows x h-half per thread ----
    {
        const int hs = t & 1;                    // h-half: h in [hs*64, hs*64+64)
        const int kg = (t >> 1) & 7;             // k = kg + 8*kk
        const int rg = t >> 4;                   // rows 2rg, 2rg+1
        const float* rp0 = tile + (2 * rg) * TS;
        const float* rp1 = rp0 + TS;
        const float sgn = (kg & 1) ? -1.f : 1.f;
        const int hb = hs * 64;

        float cA[4], sA[4], cB[4], sB[4], t2[4];
        float xr[4][2], xi[4][2];
        #pragma unroll
        for (int kk = 0; kk < 4; ++kk) {
            const int k = kg + 8 * kk;
            float sd, cd; sincosf(PI2_256 * (float)k, &sd, &cd);
            t2[kk] = 2.f * cd;
            float ss, cc;
            sincosf(PI2_256 * (float)((k * hb) & 255), &ss, &cc);
            cA[kk] = cc; sA[kk] = ss;
            sincosf(PI2_256 * (float)((k * (hb - 1)) & 255), &ss, &cc);
            cB[kk] = cc; sB[kk] = ss;
        }
        const float x0_0 = rp0[0] * 0.5f, x128_0 = rp0[128];
        const float x0_1 = rp1[0] * 0.5f, x128_1 = rp1[128];
        #pragma unroll
        for (int kk = 0; kk < 4; ++kk) {
            xr[kk][0] = (hs == 0) ? (sgn * x128_0 - x0_0) : 0.f;
            xr[kk][1] = (hs == 0) ? (sgn * x128_1 - x0_1) : 0.f;
            xi[kk][0] = 0.f; xi[kk][1] = 0.f;
        }
        for (int hq = 0; hq < 16; ++hq) {
            const float4 ye0 = *(const float4*)(rp0 + hb + hq * 4);
            const float4 yo0 = *(const float4*)(rp0 + 128 + hb + hq * 4);
            const float4 ye1 = *(const float4*)(rp1 + hb + hq * 4);
            const float4 yo1 = *(const float4*)(rp1 + 128 + hb + hq * 4);
            #pragma unroll
            for (int j = 0; j < 4; ++j) {
                const float e0 = (&ye0.x)[j], o0 = (&yo0.x)[j];
                const float e1 = (&ye1.x)[j], o1 = (&yo1.x)[j];
                #pragma unroll
                for (int kk = 0; kk < 4; ++kk) {
                    xr[kk][0] += e0 * cA[kk];  xi[kk][0] -= o0 * sA[kk];
                    xr[kk][1] += e1 * cA[kk];  xi[kk][1] -= o1 * sA[kk];
                    const float cn = t2[kk] * cA[kk] - cB[kk]; cB[kk] = cA[kk]; cA[kk] = cn;
                    const float sn = t2[kk] * sA[kk] - sB[kk]; sB[kk] = sA[kk]; sA[kk] = sn;
                }
            }
        }
        // combine the two h-halves (lane pairs differ in bit 0)
        #pragma unroll
        for (int kk = 0; kk < 4; ++kk)
            #pragma unroll
            for (int r = 0; r < 2; ++r) {
                xr[kk][r] += __shfl_xor(xr[kk][r], 1);
                xi[kk][r] += __shfl_xor(xi[kk][r], 1);
            }
        if (hs == 0) {
            #pragma unroll
            for (int kk = 0; kk < 4; ++kk) {
                const int k = kg + 8 * kk;
                XrL[(2 * rg    ) * 36 + k] = xr[kk][0];
                XiL[(2 * rg    ) * 36 + k] = xi[kk][0];
                XrL[(2 * rg + 1) * 36 + k] = xr[kk][1];
                XiL[(2 * rg + 1) * 36 + k] = xi[kk][1];
            }
        }
    }
    __syncthreads();

    // ---- phase B: mixW, scale folded; write 64-real spectral row to global ----
    {
        const int kq = t & 7, o = t >> 3;
        const int k4 = kq * 4;
        float4 ar = {0,0,0,0}, ai = {0,0,0,0};
        const float* wrb = w2r + (size_t)g * 32768 + o * 32 + k4;   // + i*1024
        const float* wib = w2i + (size_t)g * 32768 + o * 32 + k4;
        for (int i = 0; i < 32; ++i) {
            const float4 xr = *(const float4*)(XrL + i * 36 + k4);
            const float4 xi = *(const float4*)(XiL + i * 36 + k4);
            const float4 wr = *(const float4*)(wrb + i * 1024);
            const float4 wi = *(const float4*)(wib + i * 1024);
            ar.x += xr.x * wr.x - xi.x * wi.x;  ai.x += xr.x * wi.x + xi.x * wr.x;
            ar.y += xr.y * wr.y - xi.y * wi.y;  ai.y += xr.y * wi.y + xi.y * wr.y;
            ar.z += xr.z * wr.z - xi.z * wi.z;  ai.z += xr.z * wi.z + xi.z * wr.z;
            ar.w += xr.w * wr.w - xi.w * wi.w;  ai.w += xr.w * wi.w + xi.w * wr.w;
        }
        const float s2 = 2.f / 256.f, s1 = 1.f / 256.f;
        const float s0 = (k4 == 0) ? s1 : s2;
        float* dst = Yw + (size_t)((b * 2 + g) * 32 + o) * 16384 + (size_t)xrow * 64 + k4;
        *(float4*)(dst)      = make_float4(ar.x * s0, ar.y * s2, ar.z * s2, ar.w * s2);
        *(float4*)(dst + 32) = make_float4(ai.x * s0, ai.y * s2, ai.z * s2, ai.w * s2);
    }
}

// ---------------------------------------------------------------------------
// K2: folded DFT_H per channel c. Chebyshev trig (sincosf seeds).
// thread map: hs = t&1 (h-half), kg = (t>>1)&7 (4 k's), sp = t>>4 (slot quad)
// Z layout: [(bg*32 + kh)*32 + o][128]  (Re_h | Im_h)
// ---------------------------------------------------------------------------
__global__ __launch_bounds__(256) void h_fwd(const float* __restrict__ Yw,
                                             float* __restrict__ Z) {
    __shared__ float YL[256 * 64];   // 64 KB
    const int bid = blockIdx.x;      // (b*2+g)*32 + o
    const int t = threadIdx.x;
    {
        const float* src = Yw + (size_t)bid * 16384;
        #pragma unroll
        for (int r = 0; r < 16; ++r) {
            const int f = t + r * 256;
            *(float4*)(YL + f * 4) = *(const float4*)(src + f * 4);
        }
    }
    __syncthreads();

    const int hs = t & 1, kg = (t >> 1) & 7, sp = t >> 4;  // slots 4sp..4sp+3
    const int hb = hs * 64;
    const float sgn = (kg & 1) ? -1.f : 1.f;
    const float4 y0q   = *(const float4*)(YL + sp * 4);
    const float4 y128q = *(const float4*)(YL + 128 * 64 + sp * 4);

    float cA[4], sA[4], cB[4], sB[4], t2[4];
    float xr[4][4], xi[4][4];
    #pragma unroll
    for (int kk = 0; kk < 4; ++kk) {
        const int k = kg + 8 * kk;
        float sd, cd; sincosf(PI2_256 * (float)k, &sd, &cd);
        t2[kk] = 2.f * cd;
        float ss, cc;
        sincosf(PI2_256 * (float)((k * hb) & 255), &ss, &cc);
        cA[kk] = cc; sA[kk] = ss;
        sincosf(PI2_256 * (float)((k * (hb - 1)) & 255), &ss, &cc);
        cB[kk] = cc; sB[kk] = ss;
        #pragma unroll
        for (int j = 0; j < 4; ++j) {
            xr[kk][j] = (hs == 0) ? (sgn * (&y128q.x)[j] - (&y0q.x)[j]) : 0.f;
            xi[kk][j] = 0.f;
        }
    }
    for (int h = hb; h < hb + 64; ++h) {
        const float4 aq = *(const float4*)(YL + h * 64 + sp * 4);
        const float4 mq = *(const float4*)(YL + ((256 - h) & 255) * 64 + sp * 4);
        float ye[4], yo[4];
        #pragma unroll
        for (int j = 0; j < 4; ++j) {
            ye[j] = (&aq.x)[j] + (&mq.x)[j];
            yo[j] = (&aq.x)[j] - (&mq.x)[j];
        }
        #pragma unroll
        for (int kk = 0; kk < 4; ++kk) {
            #pragma unroll
            for (int j = 0; j < 4; ++j) {
                xr[kk][j] += ye[j] * cA[kk];
                xi[kk][j] -= yo[j] * sA[kk];
            }
            const float cn = t2[kk] * cA[kk] - cB[kk]; cB[kk] = cA[kk]; cA[kk] = cn;
            const float sn = t2[kk] * sA[kk] - sB[kk]; sB[kk] = sA[kk]; sA[kk] = sn;
        }
    }
    // combine h-halves (lane pairs)
    #pragma unroll
    for (int kk = 0; kk < 4; ++kk)
        #pragma unroll
        for (int j = 0; j < 4; ++j) {
            xr[kk][j] += __shfl_xor(xr[kk][j], 1);
            xi[kk][j] += __shfl_xor(xi[kk][j], 1);
        }
    if (hs == 0) {
        const int o = bid & 31, bg = bid >> 5;
        #pragma unroll
        for (int kk = 0; kk < 4; ++kk) {
            const int k = kg + 8 * kk;
            const size_t zi_ = (((size_t)bg * 32 + k) * 32 + o) * 128 + sp * 4;
            *(float4*)(Z + zi_)      = make_float4(xr[kk][0], xr[kk][1], xr[kk][2], xr[kk][3]);
            *(float4*)(Z + zi_ + 64) = make_float4(xi[kk][0], xi[kk][1], xi[kk][2], xi[kk][3]);
        }
    }
}

// ---------------------------------------------------------------------------
// K3: mixH per (b,g,kh); H-ortho scale folded. Z2: [(bg*32+o)*32+kh][128]
// ---------------------------------------------------------------------------
__global__ __launch_bounds__(256) void h_mix2(const float* __restrict__ Z,
                                              const float* __restrict__ w1r,
                                              const float* __restrict__ w1i,
                                              float* __restrict__ Z2) {
    __shared__ float ZL[32 * 128];          // [i][128] 16 KB
    __shared__ float WrL[1024], WiL[1024];  // [i*32+o] 8 KB
    const int bid = blockIdx.x;             // bg*32 + kh
    const int kh = bid & 31, bg = bid >> 5;
    const int g = bg & 1;
    const int t = threadIdx.x;
    {
        const float* src = Z + (size_t)bid * 4096;
        #pragma unroll
        for (int r = 0; r < 4; ++r) {
            const int f = t + r * 256;
            *(float4*)(ZL + f * 4) = *(const float4*)(src + f * 4);
        }
        #pragma unroll
        for (int r = 0; r < 4; ++r) {
            const int idx = t + r * 256;    // i = idx>>5, o = idx&31
            const int gidx = g * 32768 + (idx >> 5) * 1024 + (idx & 31) * 32 + kh;
            WrL[idx] = w1r[gidx];
            WiL[idx] = w1i[gidx];
        }
    }
    __syncthreads();

    const int s = t & 63, og = t >> 6;      // o = og*8 + m
    float accr[8], acci[8];
    #pragma unroll
    for (int m = 0; m < 8; ++m) { accr[m] = 0.f; acci[m] = 0.f; }
    for (int i = 0; i < 32; ++i) {
        const float zr = ZL[i * 128 + s];
        const float zi = ZL[i * 128 + 64 + s];
        #pragma unroll
        for (int m = 0; m < 8; ++m) {
            const int o = og * 8 + m;
            const float wr = WrL[i * 32 + o];
            const float wi = WiL[i * 32 + o];
            accr[m] += zr * wr - zi * wi;
            acci[m] += zr * wi + zi * wr;
        }
    }
    const float sck = (kh == 0) ? (1.f / 256.f) : (2.f / 256.f);
    #pragma unroll
    for (int m = 0; m < 8; ++m) {
        const int o = og * 8 + m;
        const size_t zo = ((size_t)(bg * 32 + o) * 32 + kh) * 128 + s;
        Z2[zo]      = accr[m] * sck;
        Z2[zo + 64] = acci[m] * sck;
    }
}

// ---------------------------------------------------------------------------
// K4: IDFT_H (mirror, Nyquist) per channel c. Trig staged in LDS.
// Z2[c][kh][128] -> YHg[c][h][64]   (YHg reuses the Yw region)
// ---------------------------------------------------------------------------
__global__ __launch_bounds__(256) void h_inv2(const float* __restrict__ Z2,
                                              const float* __restrict__ tc,
                                              const float* __restrict__ ts,
                                              float* __restrict__ YHg) {
    __shared__ float ZL[32 * 128];                  // 16 KB
    __shared__ float TcL[32 * 128], TsL[32 * 128];  // 16+16 KB (lower-half trig)
    const int bid = blockIdx.x;                     // channel c
    const int t = threadIdx.x;
    {
        const float* src = Z2 + (size_t)bid * 4096;
        #pragma unroll
        for (int r = 0; r < 4; ++r) {
            const int f = t + r * 256;
            *(float4*)(ZL + f * 4) = *(const float4*)(src + f * 4);
        }
        #pragma unroll
        for (int r = 0; r < 4; ++r) {
            const int q = t + r * 256;              // 0..1023
            const int k = q >> 5, hq = q & 31;
            *(float4*)(TcL + k * 128 + hq * 4) = *(const float4*)(tc + (size_t)k * 256 + hq * 4);
            *(float4*)(TsL + k * 128 + hq * 4) = *(const float4*)(ts + (size_t)k * 256 + hq * 4);
        }
    }
    __syncthreads();

    const int s = t & 63, hg = t >> 6;              // hg 0..3
    float zr[32], zi[32];
    #pragma unroll
    for (int k = 0; k < 32; ++k) {
        zr[k] = ZL[k * 128 + s];
        zi[k] = ZL[k * 128 + 64 + s];
    }
    float* dst = YHg + (size_t)bid * 16384;
    #pragma unroll
    for (int jq = 0; jq < 8; ++jq) {
        const int h0 = hg * 32 + jq * 4;            // 0..124
        float sC[4] = {0, 0, 0, 0}, sS[4] = {0, 0, 0, 0};
        #pragma unroll
        for (int k = 0; k < 32; ++k) {
            const float4 c4 = *(const float4*)(TcL + k * 128 + h0);  // wave-uniform
            const float4 s4 = *(const float4*)(TsL + k * 128 + h0);
            sC[0] += zr[k] * c4.x;  sS[0] += zi[k] * s4.x;
            sC[1] += zr[k] * c4.y;  sS[1] += zi[k] * s4.y;
            sC[2] += zr[k] * c4.z;  sS[2] += zi[k] * s4.z;
            sC[3] += zr[k] * c4.w;  sS[3] += zi[k] * s4.w;
        }
        #pragma unroll
        for (int jj = 0; jj < 4; ++jj) {
            const int h = h0 + jj;
            dst[h * 64 + s] = sC[jj] - sS[jj];
            if (h > 0) dst[(256 - h) * 64 + s] = sC[jj] + sS[jj];
        }
    }
    if (hg == 0) {                                  // Nyquist row h = 128
        float ny = 0.f;
        #pragma unroll
        for (int k = 0; k < 32; ++k) ny += (k & 1) ? -zr[k] : zr[k];
        dst[128 * 64 + s] = ny;
    }
}

// ---------------------------------------------------------------------------
// K5: IDFT_W (mirror, Nyquist). block = (c, hb): 32 h-rows. Trig in LDS.
// R12: mirror half assembled via width-32 shuffles -> ALL stores are float4.
// YHg[c][h][64] -> out[c][h][256]
// ---------------------------------------------------------------------------
__global__ __launch_bounds__(256) void w_inv2(const float* __restrict__ YHg,
                                              const float* __restrict__ tc,
                                              const float* __restrict__ ts,
                                              float* __restrict__ out) {
    __shared__ float YL[32 * 64];                   // 8 KB  [hl][64]
    __shared__ float TcL[32 * 128], TsL[32 * 128];  // 32 KB (lower-half trig)
    const int bid = blockIdx.x;
    const int hb = bid & 7, c = bid >> 3;
    const int t = threadIdx.x;
    {
        const float* src = YHg + (size_t)c * 16384 + hb * 2048;
        #pragma unroll
        for (int r = 0; r < 2; ++r) {
            const int f = t + r * 256;
            *(float4*)(YL + f * 4) = *(const float4*)(src + f * 4);
        }
        #pragma unroll
        for (int r = 0; r < 4; ++r) {
            const int q = t + r * 256;              // 0..1023
            const int k = q >> 5, wq_ = q & 31;
            *(float4*)(TcL + k * 128 + wq_ * 4) = *(const float4*)(tc + (size_t)k * 256 + wq_ * 4);
            *(float4*)(TsL + k * 128 + wq_ * 4) = *(const float4*)(ts + (size_t)k * 256 + wq_ * 4);
        }
    }
    __syncthreads();

    const int wq = t & 31, hh = t >> 5;             // 4 h-rows per thread
    const int w0 = wq * 4;
    float* outp = out + (size_t)c * 65536;

    float sC[4][4], sS[4][4];                       // [j][w-lane]
    float nyA[4];                                   // Nyquist accum (uniform per row)
    #pragma unroll
    for (int j = 0; j < 4; ++j) {
        nyA[j] = 0.f;
        #pragma unroll
        for (int jj = 0; jj < 4; ++jj) { sC[j][jj] = 0.f; sS[j][jj] = 0.f; }
    }

    for (int k = 0; k < 32; ++k) {
        const float4 c4 = *(const float4*)(TcL + k * 128 + w0);
        const float4 s4 = *(const float4*)(TsL + k * 128 + w0);
        const float sk = (k & 1) ? -1.f : 1.f;
        #pragma unroll
        for (int j = 0; j < 4; ++j) {
            const int hl = hh * 4 + j;
            const float R = YL[hl * 64 + k];
            const float I = YL[hl * 64 + 32 + k];
            nyA[j] += sk * R;
            sC[j][0] += R * c4.x;  sS[j][0] += I * s4.x;
            sC[j][1] += R * c4.y;  sS[j][1] += I * s4.y;
            sC[j][2] += R * c4.z;  sS[j][2] += I * s4.z;
            sC[j][3] += R * c4.w;  sS[j][3] += I * s4.w;
        }
    }
    #pragma unroll
    for (int j = 0; j < 4; ++j) {
        const int h = hb * 32 + hh * 4 + j;
        // lower half [0..127]: coalesced float4
        *(float4*)(outp + (size_t)h * 256 + w0) =
            make_float4(sC[j][0] - sS[j][0], sC[j][1] - sS[j][1],
                        sC[j][2] - sS[j][2], sC[j][3] - sS[j][3]);
        // upper half [128..255]: lane wq stores out[128+4wq .. 128+4wq+3]
        //   out[128+4wq+0] = (wq==0) ? Nyquist : val_plus(w=128-4wq) = lane(32-wq).p0
        //   out[128+4wq+1] = val_plus(127-4wq) = lane(31-wq).p3
        //   out[128+4wq+2] = val_plus(126-4wq) = lane(31-wq).p2
        //   out[128+4wq+3] = val_plus(125-4wq) = lane(31-wq).p1
        const float p0 = sC[j][0] + sS[j][0];
        const float p1 = sC[j][1] + sS[j][1];
        const float p2 = sC[j][2] + sS[j][2];
        const float p3 = sC[j][3] + sS[j][3];
        const float m0s = __shfl(p0, 32 - wq, 32);  // wq==0 wraps to lane 0 (unused)
        const float m0  = (wq == 0) ? nyA[j] : m0s;
        const float m1  = __shfl(p3, 31 - wq, 32);
        const float m2  = __shfl(p2, 31 - wq, 32);
        const float m3  = __shfl(p1, 31 - wq, 32);
        *(float4*)(outp + (size_t)h * 256 + 128 + w0) = make_float4(m0, m1, m2, m3);
    }
}

// ---------------------------------------------------------------------------
extern "C" void kernel_launch(void* const* d_in, const int* in_sizes, int n_in,
                              void* d_out, int out_size, void* d_ws, size_t ws_size,
                              hipStream_t stream) {
    const float* x   = (const float*)d_in[0];
    const float* w1r = (const float*)d_in[1];
    const float* w1i = (const float*)d_in[2];
    const float* w2r = (const float*)d_in[3];
    const float* w2i = (const float*)d_in[4];
    float* out = (float*)d_out;
    float* ws  = (float*)d_ws;

    float* tc = ws;                    //  8192 floats
    float* ts = ws + 8192;             //  8192 floats
    float* Yw = ws + 16384;            //  8,388,608 floats (33.5 MB) — reused as YHg
    float* Z  = Yw + 8388608;          //  2,097,152 floats ( 8.4 MB)
    float* Z2 = Z + 2097152;           //  2,097,152 floats ( 8.4 MB)

    init_tab<<<32, 256, 0, stream>>>(tc, ts);
    w_fwd<<<4096, 256, 0, stream>>>(x, w2r, w2i, Yw);
    h_fwd<<<512, 256, 0, stream>>>(Yw, Z);
    h_mix2<<<512, 256, 0, stream>>>(Z, w1r, w1i, Z2);
    h_inv2<<<512, 256, 0, stream>>>(Z2, tc, ts, Yw);   // Yw region reused as YH
    w_inv2<<<4096, 256, 0, stream>>>(Yw, tc, ts, out);
}